// Round 3
// baseline (115.149 us; speedup 1.0000x reference)
//
#include <hip/hip_runtime.h>

#define DEV __device__ __forceinline__

typedef __bf16 bf16;
typedef __bf16 bf16x8 __attribute__((ext_vector_type(8)));
typedef float f32x4 __attribute__((ext_vector_type(4)));

#define B_ 2
#define D_ 512
#define N_ 2048
#define H_ 8
#define MD_ 64
// 1/sqrt(512) * log2(e): scores pre-scaled so softmax uses exp2 directly
#define SCALE_F (0.04419417382415922f * 1.4426950408889634f)

DEV void gload_lds16(const void* g, void* l) {
  __builtin_amdgcn_global_load_lds(
      (const __attribute__((address_space(1))) void*)g,
      (__attribute__((address_space(3))) void*)l, 16, 0, 0);
}

DEV f32x4 mfma16(bf16x8 a, bf16x8 b, f32x4 c) {
  return __builtin_amdgcn_mfma_f32_16x16x32_bf16(a, b, c, 0, 0, 0);
}

// ---------------------------------------------------------------------------
// prep_w: rows 0..1535 -> Wf bf16 (Wq*SCALE | Wk | Wv), bias_f (bq*SCALE|bk|bv)
//         rows 1536..2047 -> Wo_r[r][h*64+d] = Wo[r][d*8+h]  (bf16)
// ---------------------------------------------------------------------------
__global__ __launch_bounds__(256) void prep_w(
    const float* __restrict__ Wq, const float* __restrict__ bq,
    const float* __restrict__ Wk, const float* __restrict__ bk,
    const float* __restrict__ Wv, const float* __restrict__ bv,
    const float* __restrict__ Wo,
    bf16* __restrict__ Wf, float* __restrict__ biasf, bf16* __restrict__ Wor) {
  int row = blockIdx.x;
  int t = threadIdx.x;
  if (row < 1536) {
    const float* src;
    float scale = 1.0f;
    if (row < 512)       { src = Wq + (size_t)row * 512; scale = SCALE_F; }
    else if (row < 1024) { src = Wk + (size_t)(row - 512) * 512; }
    else                 { src = Wv + (size_t)(row - 1024) * 512; }
    for (int c = t; c < 512; c += 256)
      Wf[(size_t)row * 512 + c] = (bf16)(src[c] * scale);
    if (t == 0) {
      float bb;
      if (row < 512)       bb = bq[row] * SCALE_F;
      else if (row < 1024) bb = bk[row - 512];
      else                 bb = bv[row - 1024];
      biasf[row] = bb;
    }
  } else {
    int r = row - 1536;
    for (int c2 = t; c2 < 512; c2 += 256) {
      int hh = c2 >> 6, dd = c2 & 63;
      Wor[(size_t)r * 512 + c2] = (bf16)Wo[(size_t)r * 512 + dd * 8 + hh];
    }
  }
}

// ---------------------------------------------------------------------------
// prep_qt: Qt[b][n][c] = bf16(Q[b][c][n])   (64x64 tiles through LDS)
// grid (N/64, D/64, B), block 256
// ---------------------------------------------------------------------------
__global__ __launch_bounds__(256) void prep_qt(const float* __restrict__ Q,
                                               bf16* __restrict__ Qt) {
  __shared__ float tile[64][65];
  int b = blockIdx.z;
  int d0 = blockIdx.y * 64;
  int n0 = blockIdx.x * 64;
  int t = threadIdx.x;
  int r = t >> 2, cw = t & 3;

  const float* src = Q + ((size_t)(b * 512 + d0 + r)) * 2048 + n0 + cw * 16;
#pragma unroll
  for (int e4 = 0; e4 < 4; ++e4) {
    float4 v = *(const float4*)(src + e4 * 4);
    tile[r][cw * 16 + e4 * 4 + 0] = v.x;
    tile[r][cw * 16 + e4 * 4 + 1] = v.y;
    tile[r][cw * 16 + e4 * 4 + 2] = v.z;
    tile[r][cw * 16 + e4 * 4 + 3] = v.w;
  }
  __syncthreads();
  bf16x8 o0{}, o1{};
#pragma unroll
  for (int e = 0; e < 8; ++e) {
    o0[e] = (bf16)tile[cw * 16 + e][r];
    o1[e] = (bf16)tile[cw * 16 + 8 + e][r];
  }
  bf16* dst = Qt + ((size_t)(b * 2048 + n0 + r)) * 512 + d0 + cw * 16;
  *(bf16x8*)dst = o0;
  *((bf16x8*)dst + 1) = o1;
}

// ---------------------------------------------------------------------------
// qkv_gemm: C[c][p] = sum_k Wf[c][k] * Qt[b][p][k] + bias[c]
// 128x128 tile, BK=32, 4 waves (2x2), 4x4 frags/wave, global_load_lds staging.
// Epilogue: c<512 -> qp[b][h][p][d]; c<1024 -> kp; else vn[b][c][p]
// grid (12, 16, 2)
// ---------------------------------------------------------------------------
__global__ __launch_bounds__(256) void qkv_gemm(
    const bf16* __restrict__ Wf, const bf16* __restrict__ Qt,
    const float* __restrict__ biasf,
    bf16* __restrict__ qp, bf16* __restrict__ kp, bf16* __restrict__ vn) {
  __shared__ bf16 Al[128 * 32];
  __shared__ bf16 Bl[128 * 32];
  int b = blockIdx.z;
  int c0 = blockIdx.x * 128;
  int p0 = blockIdx.y * 128;
  int tid = threadIdx.x, w = tid >> 6, lane = tid & 63;
  int wm = w >> 1, wn = w & 1;
  int g = lane >> 4, l15 = lane & 15;

  const bf16* Abase = Wf + (size_t)c0 * 512;
  const bf16* Bbase = Qt + ((size_t)b * 2048 + p0) * 512;

  f32x4 acc[4][4] = {};

  for (int ks = 0; ks < 16; ++ks) {
    int k0 = ks * 32;
    __syncthreads();
#pragma unroll
    for (int i = 0; i < 2; ++i) {
      int rowl = w * 32 + i * 16 + (lane >> 2);
      int ch = lane & 3;
      gload_lds16(Abase + (size_t)rowl * 512 + k0 + ch * 8,
                  Al + (w * 32 + i * 16) * 32);
      gload_lds16(Bbase + (size_t)rowl * 512 + k0 + ch * 8,
                  Bl + (w * 32 + i * 16) * 32);
    }
    __syncthreads();
    bf16x8 a[4], bb[4];
#pragma unroll
    for (int mi = 0; mi < 4; ++mi)
      a[mi] = *(const bf16x8*)(Al + (wm * 64 + mi * 16 + l15) * 32 + g * 8);
#pragma unroll
    for (int ni = 0; ni < 4; ++ni)
      bb[ni] = *(const bf16x8*)(Bl + (wn * 64 + ni * 16 + l15) * 32 + g * 8);
#pragma unroll
    for (int mi = 0; mi < 4; ++mi)
#pragma unroll
      for (int ni = 0; ni < 4; ++ni)
        acc[mi][ni] = mfma16(a[mi], bb[ni], acc[mi][ni]);
  }

#pragma unroll
  for (int mi = 0; mi < 4; ++mi) {
#pragma unroll
    for (int ni = 0; ni < 4; ++ni) {
#pragma unroll
      for (int r = 0; r < 4; ++r) {
        int row = c0 + wm * 64 + mi * 16 + g * 4 + r;
        int p = p0 + wn * 64 + ni * 16 + l15;
        float val = acc[mi][ni][r] + biasf[row];
        bf16 hv = (bf16)val;
        if (row < 512) {
          int c = row;
          qp[(((size_t)b * 8 + (c & 7)) * 2048 + p) * 64 + (c >> 3)] = hv;
        } else if (row < 1024) {
          int c = row - 512;
          kp[(((size_t)b * 8 + (c & 7)) * 2048 + p) * 64 + (c >> 3)] = hv;
        } else {
          int c = row - 1024;
          vn[((size_t)b * 512 + c) * 2048 + p] = hv;
        }
      }
    }
  }
}

// ---------------------------------------------------------------------------
// attn_k v3: flash attention, KV-split x2. Block = 64 queries, 4 waves.
// grid (32 qblk, 16 bh, 2 split). Each block does 16 KV steps of 64.
// Q held in registers (no Qs LDS) -> LDS 40KB -> 4 blocks/CU.
// Double-buffered K/V staging, 1 barrier/step, setprio around MFMA.
// Writes unnormalized O-partial (bf16) + per-row m,l (f32, log2 domain).
// ---------------------------------------------------------------------------
__global__ __launch_bounds__(256) void attn_k(
    const bf16* __restrict__ qp, const bf16* __restrict__ kp,
    const bf16* __restrict__ vn, bf16* __restrict__ Op,
    float* __restrict__ mbuf, float* __restrict__ lbuf) {
  __shared__ bf16 Ks[2][64 * 64];
  __shared__ bf16 Vs[2][64 * 64];
  __shared__ bf16 Ps[64 * 64];
  int q0 = blockIdx.x * 64;
  int bh = blockIdx.y;            // b*8 + h
  int z = blockIdx.z;             // kv split
  int b = bh >> 3, h = bh & 7;
  int tid = threadIdx.x, w = tid >> 6, lane = tid & 63;
  int g = lane >> 4, l15 = lane & 15;
  int irow = w * 16 + l15;

  // Q A-fragments straight to registers (reused all 16 steps)
  bf16x8 qreg[2];
#pragma unroll
  for (int ks2 = 0; ks2 < 2; ++ks2)
    qreg[ks2] = *(const bf16x8*)(qp + ((size_t)bh * 2048 + q0 + irow) * 64 +
                                 ks2 * 32 + g * 8);

  // per-lane staging coords (swizzled global source, linear LDS dest)
  int srow = w * 16 + (lane >> 3);          // +8 for i=1
  int sch = lane & 7;

  const bf16* Kall = kp + (size_t)bh * 2048 * 64 + (size_t)z * 16 * 64 * 64;
  const bf16* Vall = vn + ((size_t)(b * 512 + h)) * 2048 + (size_t)z * 16 * 64;

  // stage K/V local step 0 into buffer 0
#pragma unroll
  for (int i = 0; i < 2; ++i) {
    int row = srow + i * 8;
    int ch = sch ^ (row & 7);
    gload_lds16(Kall + (size_t)row * 64 + ch * 8, Ks[0] + (w * 16 + i * 8) * 64);
    gload_lds16(Vall + (size_t)row * 16384 + ch * 8, Vs[0] + (w * 16 + i * 8) * 64);
  }

  f32x4 oacc[4] = {};
  float mrow[4], rs_acc[4];
#pragma unroll
  for (int r = 0; r < 4; ++r) { mrow[r] = -1e30f; rs_acc[r] = 0.0f; }

  __syncthreads();  // step-0 staging drained (vmcnt(0) inside)

  for (int t = 0; t < 16; ++t) {
    int cur = t & 1, nxt = cur ^ 1;
    int tn = (t < 15) ? t + 1 : 15;  // clamp (redundant last prefetch)

    // issue next-step staging (lands during compute; drained at loop-end sync)
    const bf16* Kbase = Kall + (size_t)tn * 64 * 64;
    const bf16* Vbase = Vall + (size_t)tn * 64;
#pragma unroll
    for (int i = 0; i < 2; ++i) {
      int row = srow + i * 8;
      int ch = sch ^ (row & 7);
      gload_lds16(Kbase + (size_t)row * 64 + ch * 8,
                  Ks[nxt] + (w * 16 + i * 8) * 64);
      gload_lds16(Vbase + (size_t)row * 16384 + ch * 8,
                  Vs[nxt] + (w * 16 + i * 8) * 64);
    }

    // S = Q K^T for this wave's 16-row strip
    f32x4 s[4] = {};
    __builtin_amdgcn_s_setprio(1);
#pragma unroll
    for (int ks2 = 0; ks2 < 2; ++ks2) {
#pragma unroll
      for (int jt = 0; jt < 4; ++jt) {
        int jrow = jt * 16 + l15;
        bf16x8 kb = *(const bf16x8*)(Ks[cur] + jrow * 64 + (((ks2 * 4 + g) ^ (jrow & 7)) << 3));
        s[jt] = mfma16(qreg[ks2], kb, s[jt]);
      }
    }
    __builtin_amdgcn_s_setprio(0);

    // online softmax with defer-max (THR=8 in log2 units)
    float nm[4];
    float grow = -1e30f;
#pragma unroll
    for (int r = 0; r < 4; ++r) {
      float rm = fmaxf(fmaxf(s[0][r], s[1][r]), fmaxf(s[2][r], s[3][r]));
      rm = fmaxf(rm, __shfl_xor(rm, 1));
      rm = fmaxf(rm, __shfl_xor(rm, 2));
      rm = fmaxf(rm, __shfl_xor(rm, 4));
      rm = fmaxf(rm, __shfl_xor(rm, 8));
      nm[r] = fmaxf(mrow[r], rm);
      grow = fmaxf(grow, rm - mrow[r]);
    }
    if (__any(grow > 8.0f)) {
#pragma unroll
      for (int r = 0; r < 4; ++r) {
        float esc = __builtin_amdgcn_exp2f(mrow[r] - nm[r]);
        mrow[r] = nm[r];
        rs_acc[r] *= esc;
#pragma unroll
        for (int dt = 0; dt < 4; ++dt) oacc[dt][r] *= esc;
      }
    }
#pragma unroll
    for (int jt = 0; jt < 4; ++jt) {
#pragma unroll
      for (int r = 0; r < 4; ++r) {
        float pv = __builtin_amdgcn_exp2f(s[jt][r] - mrow[r]);
        rs_acc[r] += pv;  // per-lane partial; reduced once at the end
        int iw = w * 16 + g * 4 + r;
        int j = jt * 16 + l15;
        Ps[iw * 64 + (j ^ ((iw & 7) << 3))] = (bf16)pv;
      }
    }

    // O += P V   (Ps is wave-private: lgkmcnt ordering only, no barrier)
    __builtin_amdgcn_s_setprio(1);
#pragma unroll
    for (int ks2 = 0; ks2 < 2; ++ks2) {
      bf16x8 pa = *(const bf16x8*)(Ps + irow * 64 + (((ks2 * 4 + g) ^ (irow & 7)) << 3));
#pragma unroll
      for (int dt = 0; dt < 4; ++dt) {
        int drow = dt * 16 + l15;
        bf16x8 vb = *(const bf16x8*)(Vs[cur] + drow * 64 + (((ks2 * 4 + g) ^ (drow & 7)) << 3));
        oacc[dt] = mfma16(pa, vb, oacc[dt]);
      }
    }
    __builtin_amdgcn_s_setprio(0);

    __syncthreads();  // drains next-step staging + releases buf[cur] for reuse
  }

  // final l: reduce per-lane partials across the 16-lane row groups
  float lrow[4];
#pragma unroll
  for (int r = 0; r < 4; ++r) {
    float t2 = rs_acc[r];
    t2 += __shfl_xor(t2, 1);
    t2 += __shfl_xor(t2, 2);
    t2 += __shfl_xor(t2, 4);
    t2 += __shfl_xor(t2, 8);
    lrow[r] = t2;
  }

  // epilogue: UNNORMALIZED partial O (bf16) + m,l per row
  size_t zoff = (size_t)z * 16 * 2048;
#pragma unroll
  for (int dt = 0; dt < 4; ++dt) {
#pragma unroll
    for (int r = 0; r < 4; ++r) {
      int i = w * 16 + g * 4 + r;
      Op[(zoff + (size_t)bh * 2048 + q0 + i) * 64 + dt * 16 + l15] =
          (bf16)oacc[dt][r];
    }
  }
  if (l15 == 0) {
#pragma unroll
    for (int r = 0; r < 4; ++r) {
      int i = w * 16 + g * 4 + r;
      mbuf[zoff + (size_t)bh * 2048 + q0 + i] = mrow[r];
      lbuf[zoff + (size_t)bh * 2048 + q0 + i] = lrow[r];
    }
  }
}

// ---------------------------------------------------------------------------
// combine: oh[row][d] = (w0*O0 + w1*O1) / (w0*l0 + w1*l1), w_z = 2^(m_z - M)
// 131072 threads: thread = (row, 16-d chunk). grid 512, block 256.
// ---------------------------------------------------------------------------
__global__ __launch_bounds__(256) void combine(
    const bf16* __restrict__ Op, const float* __restrict__ mbuf,
    const float* __restrict__ lbuf, bf16* __restrict__ oh) {
  int idx = blockIdx.x * 256 + threadIdx.x;
  int row = idx >> 2;
  int dc = (idx & 3) * 16;
  float m0 = mbuf[row], m1 = mbuf[32768 + row];
  float l0 = lbuf[row], l1 = lbuf[32768 + row];
  float M = fmaxf(m0, m1);
  float w0 = __builtin_amdgcn_exp2f(m0 - M);
  float w1 = __builtin_amdgcn_exp2f(m1 - M);
  float invL = 1.0f / (w0 * l0 + w1 * l1);
  float a0 = w0 * invL, a1 = w1 * invL;

  const bf16x8* p0 = (const bf16x8*)(Op + (size_t)row * 64 + dc);
  const bf16x8* p1 = (const bf16x8*)(Op + (size_t)32768 * 64 + (size_t)row * 64 + dc);
  bf16x8* po = (bf16x8*)(oh + (size_t)row * 64 + dc);
#pragma unroll
  for (int v = 0; v < 2; ++v) {
    bf16x8 x0 = p0[v], x1 = p1[v];
    bf16x8 o;
#pragma unroll
    for (int e = 0; e < 8; ++e)
      o[e] = (bf16)(a0 * (float)x0[e] + a1 * (float)x1[e]);
    po[v] = o;
  }
}

// ---------------------------------------------------------------------------
// out_gemm: out[b][r][p] = sum_k Wor[r][k] * oh_as_B[p][k] + bo[r]   (fp32 out)
// grid (4, 16, 2)
// ---------------------------------------------------------------------------
__global__ __launch_bounds__(256) void out_gemm(
    const bf16* __restrict__ Wor, const bf16* __restrict__ oh,
    const float* __restrict__ bo, float* __restrict__ out) {
  __shared__ bf16 Al[128 * 32];
  __shared__ bf16 Bl[128 * 32];
  int b = blockIdx.z;
  int r0 = blockIdx.x * 128;
  int p0 = blockIdx.y * 128;
  int tid = threadIdx.x, w = tid >> 6, lane = tid & 63;
  int wm = w >> 1, wn = w & 1;
  int g = lane >> 4, l15 = lane & 15;

  const bf16* Abase = Wor + (size_t)r0 * 512;

  f32x4 acc[4][4] = {};

  for (int ks = 0; ks < 16; ++ks) {
    int k0 = ks * 32;
    int hh = k0 >> 6, d0 = k0 & 63;
    const bf16* Bbase = oh + (((size_t)b * 8 + hh) * 2048 + p0) * 64 + d0;
    __syncthreads();
#pragma unroll
    for (int i = 0; i < 2; ++i) {
      int rowl = w * 32 + i * 16 + (lane >> 2);
      int ch = lane & 3;
      gload_lds16(Abase + (size_t)rowl * 512 + k0 + ch * 8,
                  Al + (w * 32 + i * 16) * 32);
      gload_lds16(Bbase + (size_t)rowl * 64 + ch * 8,
                  Bl + (w * 32 + i * 16) * 32);
    }
    __syncthreads();
    bf16x8 a[4], bb[4];
#pragma unroll
    for (int mi = 0; mi < 4; ++mi)
      a[mi] = *(const bf16x8*)(Al + (wm * 64 + mi * 16 + l15) * 32 + g * 8);
#pragma unroll
    for (int ni = 0; ni < 4; ++ni)
      bb[ni] = *(const bf16x8*)(Bl + (wn * 64 + ni * 16 + l15) * 32 + g * 8);
#pragma unroll
    for (int mi = 0; mi < 4; ++mi)
#pragma unroll
      for (int ni = 0; ni < 4; ++ni)
        acc[mi][ni] = mfma16(a[mi], bb[ni], acc[mi][ni]);
  }

#pragma unroll
  for (int mi = 0; mi < 4; ++mi) {
#pragma unroll
    for (int ni = 0; ni < 4; ++ni) {
#pragma unroll
      for (int r = 0; r < 4; ++r) {
        int row = r0 + wm * 64 + mi * 16 + g * 4 + r;
        int p = p0 + wn * 64 + ni * 16 + l15;
        out[((size_t)b * 512 + row) * 2048 + p] = acc[mi][ni][r] + bo[row];
      }
    }
  }
}

// ---------------------------------------------------------------------------
extern "C" void kernel_launch(void* const* d_in, const int* in_sizes, int n_in,
                              void* d_out, int out_size, void* d_ws, size_t ws_size,
                              hipStream_t stream) {
  (void)in_sizes; (void)n_in; (void)out_size; (void)ws_size;
  const float* Q  = (const float*)d_in[0];
  const float* Wq = (const float*)d_in[1];
  const float* bq = (const float*)d_in[2];
  const float* Wk = (const float*)d_in[3];
  const float* bk = (const float*)d_in[4];
  const float* Wv = (const float*)d_in[5];
  const float* bv = (const float*)d_in[6];
  const float* Wo = (const float*)d_in[7];
  const float* bo = (const float*)d_in[8];
  float* out = (float*)d_out;

  char* ws = (char*)d_ws;
  bf16*  Wf    = (bf16*)(ws + 0);          // 1536*512*2  = 1572864
  bf16*  Wor   = (bf16*)(ws + 1572864);    // 512*512*2   = 524288
  float* biasf = (float*)(ws + 2097152);   // 1536*4      = 6144
  bf16*  Qt    = (bf16*)(ws + 2103296);    // 2*2048*512*2 = 4194304
  bf16*  qp    = (bf16*)(ws + 6297600);    // 4194304
  bf16*  kp    = (bf16*)(ws + 10491904);   // 4194304
  bf16*  vn    = (bf16*)(ws + 14686208);   // 4194304
  bf16*  oh    = (bf16*)(ws + 18880512);   // 4194304  (ends 23074816)
  bf16*  Opart = (bf16*)(ws + 23074816);   // 2*16*2048*64*2 = 8388608
  float* mbuf  = (float*)(ws + 31463424);  // 2*16*2048*4 = 262144
  float* lbuf  = (float*)(ws + 31725568);  // 262144 (ends ~32.0 MB)

  prep_w<<<dim3(2048), dim3(256), 0, stream>>>(Wq, bq, Wk, bk, Wv, bv, Wo,
                                               Wf, biasf, Wor);
  prep_qt<<<dim3(32, 8, 2), dim3(256), 0, stream>>>(Q, Qt);
  qkv_gemm<<<dim3(12, 16, 2), dim3(256), 0, stream>>>(Wf, Qt, biasf, qp, kp, vn);
  attn_k<<<dim3(32, 16, 2), dim3(256), 0, stream>>>(qp, kp, vn, Opart, mbuf, lbuf);
  combine<<<dim3(512), dim3(256), 0, stream>>>(Opart, mbuf, lbuf, oh);
  out_gemm<<<dim3(4, 16, 2), dim3(256), 0, stream>>>(Wor, oh, bo, out);
}

// Round 4
// 99.822 us; speedup vs baseline: 1.1535x; 1.1535x over previous
//
#include <hip/hip_runtime.h>

#define DEV __device__ __forceinline__

typedef __bf16 bf16;
typedef __bf16 bf16x8 __attribute__((ext_vector_type(8)));
typedef float f32x4 __attribute__((ext_vector_type(4)));

#define B_ 2
#define D_ 512
#define N_ 2048
#define H_ 8
#define MD_ 64
// 1/sqrt(512) * log2(e): scores pre-scaled so softmax uses exp2 directly
#define SCALE_F (0.04419417382415922f * 1.4426950408889634f)

DEV void gload_lds16(const void* g, void* l) {
  __builtin_amdgcn_global_load_lds(
      (const __attribute__((address_space(1))) void*)g,
      (__attribute__((address_space(3))) void*)l, 16, 0, 0);
}

DEV f32x4 mfma16(bf16x8 a, bf16x8 b, f32x4 c) {
  return __builtin_amdgcn_mfma_f32_16x16x32_bf16(a, b, c, 0, 0, 0);
}

// ---------------------------------------------------------------------------
// prep_w: rows 0..1535 -> Wf bf16 (Wq*SCALE | Wk | Wv), bias_f (bq*SCALE|bk|bv)
//         rows 1536..2047 -> Wo_r[r][h*64+d] = Wo[r][d*8+h]  (bf16)
// ---------------------------------------------------------------------------
__global__ __launch_bounds__(256) void prep_w(
    const float* __restrict__ Wq, const float* __restrict__ bq,
    const float* __restrict__ Wk, const float* __restrict__ bk,
    const float* __restrict__ Wv, const float* __restrict__ bv,
    const float* __restrict__ Wo,
    bf16* __restrict__ Wf, float* __restrict__ biasf, bf16* __restrict__ Wor) {
  int row = blockIdx.x;
  int t = threadIdx.x;
  if (row < 1536) {
    const float* src;
    float scale = 1.0f;
    if (row < 512)       { src = Wq + (size_t)row * 512; scale = SCALE_F; }
    else if (row < 1024) { src = Wk + (size_t)(row - 512) * 512; }
    else                 { src = Wv + (size_t)(row - 1024) * 512; }
    for (int c = t; c < 512; c += 256)
      Wf[(size_t)row * 512 + c] = (bf16)(src[c] * scale);
    if (t == 0) {
      float bb;
      if (row < 512)       bb = bq[row] * SCALE_F;
      else if (row < 1024) bb = bk[row - 512];
      else                 bb = bv[row - 1024];
      biasf[row] = bb;
    }
  } else {
    int r = row - 1536;
    for (int c2 = t; c2 < 512; c2 += 256) {
      int hh = c2 >> 6, dd = c2 & 63;
      Wor[(size_t)r * 512 + c2] = (bf16)Wo[(size_t)r * 512 + dd * 8 + hh];
    }
  }
}

// ---------------------------------------------------------------------------
// prep_qt: Qt[b][n][c] = bf16(Q[b][c][n])   (64x64 tiles through LDS)
// grid (N/64, D/64, B), block 256
// ---------------------------------------------------------------------------
__global__ __launch_bounds__(256) void prep_qt(const float* __restrict__ Q,
                                               bf16* __restrict__ Qt) {
  __shared__ float tile[64][65];
  int b = blockIdx.z;
  int d0 = blockIdx.y * 64;
  int n0 = blockIdx.x * 64;
  int t = threadIdx.x;
  int r = t >> 2, cw = t & 3;

  const float* src = Q + ((size_t)(b * 512 + d0 + r)) * 2048 + n0 + cw * 16;
#pragma unroll
  for (int e4 = 0; e4 < 4; ++e4) {
    float4 v = *(const float4*)(src + e4 * 4);
    tile[r][cw * 16 + e4 * 4 + 0] = v.x;
    tile[r][cw * 16 + e4 * 4 + 1] = v.y;
    tile[r][cw * 16 + e4 * 4 + 2] = v.z;
    tile[r][cw * 16 + e4 * 4 + 3] = v.w;
  }
  __syncthreads();
  bf16x8 o0{}, o1{};
#pragma unroll
  for (int e = 0; e < 8; ++e) {
    o0[e] = (bf16)tile[cw * 16 + e][r];
    o1[e] = (bf16)tile[cw * 16 + 8 + e][r];
  }
  bf16* dst = Qt + ((size_t)(b * 2048 + n0 + r)) * 512 + d0 + cw * 16;
  *(bf16x8*)dst = o0;
  *((bf16x8*)dst + 1) = o1;
}

// ---------------------------------------------------------------------------
// qkv_gemm: C[c][p] = sum_k Wf[c][k] * Qt[b][p][k] + bias[c]
// 128x128 tile, BK=32, 4 waves (2x2), 4x4 frags/wave, global_load_lds staging.
// Epilogue: c<512 -> qp[b][h][p][d]; c<1024 -> kp; else vn[b][c][p]
// grid (12, 16, 2)
// ---------------------------------------------------------------------------
__global__ __launch_bounds__(256) void qkv_gemm(
    const bf16* __restrict__ Wf, const bf16* __restrict__ Qt,
    const float* __restrict__ biasf,
    bf16* __restrict__ qp, bf16* __restrict__ kp, bf16* __restrict__ vn) {
  __shared__ bf16 Al[128 * 32];
  __shared__ bf16 Bl[128 * 32];
  int b = blockIdx.z;
  int c0 = blockIdx.x * 128;
  int p0 = blockIdx.y * 128;
  int tid = threadIdx.x, w = tid >> 6, lane = tid & 63;
  int wm = w >> 1, wn = w & 1;
  int g = lane >> 4, l15 = lane & 15;

  const bf16* Abase = Wf + (size_t)c0 * 512;
  const bf16* Bbase = Qt + ((size_t)b * 2048 + p0) * 512;

  f32x4 acc[4][4] = {};

  for (int ks = 0; ks < 16; ++ks) {
    int k0 = ks * 32;
    __syncthreads();
#pragma unroll
    for (int i = 0; i < 2; ++i) {
      int rowl = w * 32 + i * 16 + (lane >> 2);
      int ch = lane & 3;
      gload_lds16(Abase + (size_t)rowl * 512 + k0 + ch * 8,
                  Al + (w * 32 + i * 16) * 32);
      gload_lds16(Bbase + (size_t)rowl * 512 + k0 + ch * 8,
                  Bl + (w * 32 + i * 16) * 32);
    }
    __syncthreads();
    bf16x8 a[4], bb[4];
#pragma unroll
    for (int mi = 0; mi < 4; ++mi)
      a[mi] = *(const bf16x8*)(Al + (wm * 64 + mi * 16 + l15) * 32 + g * 8);
#pragma unroll
    for (int ni = 0; ni < 4; ++ni)
      bb[ni] = *(const bf16x8*)(Bl + (wn * 64 + ni * 16 + l15) * 32 + g * 8);
#pragma unroll
    for (int mi = 0; mi < 4; ++mi)
#pragma unroll
      for (int ni = 0; ni < 4; ++ni)
        acc[mi][ni] = mfma16(a[mi], bb[ni], acc[mi][ni]);
  }

#pragma unroll
  for (int mi = 0; mi < 4; ++mi) {
#pragma unroll
    for (int ni = 0; ni < 4; ++ni) {
#pragma unroll
      for (int r = 0; r < 4; ++r) {
        int row = c0 + wm * 64 + mi * 16 + g * 4 + r;
        int p = p0 + wn * 64 + ni * 16 + l15;
        float val = acc[mi][ni][r] + biasf[row];
        bf16 hv = (bf16)val;
        if (row < 512) {
          int c = row;
          qp[(((size_t)b * 8 + (c & 7)) * 2048 + p) * 64 + (c >> 3)] = hv;
        } else if (row < 1024) {
          int c = row - 512;
          kp[(((size_t)b * 8 + (c & 7)) * 2048 + p) * 64 + (c >> 3)] = hv;
        } else {
          int c = row - 1024;
          vn[((size_t)b * 512 + c) * 2048 + p] = hv;
        }
      }
    }
  }
}

// ---------------------------------------------------------------------------
// attn_k v4: flash attention, QBLK=128, 8 waves (512 thr), KV-split x2.
// grid (16 qblk, 16 bh, 2 split). Each block: 16 KV steps of 64.
// K/V staged ONCE per 128 queries (halves staging vs QBLK=64).
// Q in registers; K/V double-buffered; 1 barrier/step; setprio on MFMA.
// Writes unnormalized O-partial (bf16) + per-row m,l (f32, log2 domain).
// LDS: 2*8(K) + 2*8(V) + 16(Ps) = 48KB.
// ---------------------------------------------------------------------------
__global__ __launch_bounds__(512) void attn_k(
    const bf16* __restrict__ qp, const bf16* __restrict__ kp,
    const bf16* __restrict__ vn, bf16* __restrict__ Op,
    float* __restrict__ mbuf, float* __restrict__ lbuf) {
  __shared__ bf16 Ks[2][64 * 64];
  __shared__ bf16 Vs[2][64 * 64];
  __shared__ bf16 Ps[128 * 64];
  int q0 = blockIdx.x * 128;
  int bh = blockIdx.y;            // b*8 + h
  int z = blockIdx.z;             // kv split
  int b = bh >> 3, h = bh & 7;
  int tid = threadIdx.x, w = tid >> 6, lane = tid & 63;
  int g = lane >> 4, l15 = lane & 15;
  int irow = w * 16 + l15;        // this wave's q-row for MFMA A/C (0..127)

  // Q A-fragments straight to registers (reused all 16 steps)
  bf16x8 qreg[2];
#pragma unroll
  for (int ks2 = 0; ks2 < 2; ++ks2)
    qreg[ks2] = *(const bf16x8*)(qp + ((size_t)bh * 2048 + q0 + irow) * 64 +
                                 ks2 * 32 + g * 8);

  // staging coords: 512 lanes cover one 64x64 bf16 tile (8KB) in ONE
  // gload_lds16 per wave. row = tid>>3 (wave w: rows w*8..w*8+7),
  // swizzled source chunk, linear LDS dest (wave base = w*512 elem).
  int krow = tid >> 3;
  int kch = (tid & 7) ^ (krow & 7);

  const bf16* Kall = kp + (size_t)bh * 2048 * 64 + (size_t)z * 16 * 64 * 64;
  const bf16* Vall = vn + ((size_t)(b * 512 + h)) * 2048 + (size_t)z * 16 * 64;

  // stage K/V local step 0 into buffer 0
  gload_lds16(Kall + (size_t)krow * 64 + kch * 8, Ks[0] + w * 512);
  gload_lds16(Vall + (size_t)krow * 16384 + kch * 8, Vs[0] + w * 512);

  f32x4 oacc[4] = {};
  float mrow[4], rs_acc[4];
#pragma unroll
  for (int r = 0; r < 4; ++r) { mrow[r] = -1e30f; rs_acc[r] = 0.0f; }

  __syncthreads();  // step-0 staging drained (vmcnt(0) inside)

  for (int t = 0; t < 16; ++t) {
    int cur = t & 1, nxt = cur ^ 1;
    int tn = (t < 15) ? t + 1 : 15;  // clamp (redundant last prefetch)

    // issue next-step staging (lands during compute; drained at loop-end sync)
    gload_lds16(Kall + (size_t)tn * 64 * 64 + (size_t)krow * 64 + kch * 8,
                Ks[nxt] + w * 512);
    gload_lds16(Vall + (size_t)tn * 64 + (size_t)krow * 16384 + kch * 8,
                Vs[nxt] + w * 512);

    // S = Q K^T for this wave's 16-row strip
    f32x4 s[4] = {};
    __builtin_amdgcn_s_setprio(1);
#pragma unroll
    for (int ks2 = 0; ks2 < 2; ++ks2) {
#pragma unroll
      for (int jt = 0; jt < 4; ++jt) {
        int jrow = jt * 16 + l15;
        bf16x8 kb = *(const bf16x8*)(Ks[cur] + jrow * 64 + (((ks2 * 4 + g) ^ (jrow & 7)) << 3));
        s[jt] = mfma16(qreg[ks2], kb, s[jt]);
      }
    }
    __builtin_amdgcn_s_setprio(0);

    // online softmax with defer-max (THR=8 in log2 units)
    float nm[4];
    float grow = -1e30f;
#pragma unroll
    for (int r = 0; r < 4; ++r) {
      float rm = fmaxf(fmaxf(s[0][r], s[1][r]), fmaxf(s[2][r], s[3][r]));
      rm = fmaxf(rm, __shfl_xor(rm, 1));
      rm = fmaxf(rm, __shfl_xor(rm, 2));
      rm = fmaxf(rm, __shfl_xor(rm, 4));
      rm = fmaxf(rm, __shfl_xor(rm, 8));
      nm[r] = fmaxf(mrow[r], rm);
      grow = fmaxf(grow, rm - mrow[r]);
    }
    if (__any(grow > 8.0f)) {
#pragma unroll
      for (int r = 0; r < 4; ++r) {
        float esc = __builtin_amdgcn_exp2f(mrow[r] - nm[r]);
        mrow[r] = nm[r];
        rs_acc[r] *= esc;
#pragma unroll
        for (int dt = 0; dt < 4; ++dt) oacc[dt][r] *= esc;
      }
    }
#pragma unroll
    for (int jt = 0; jt < 4; ++jt) {
#pragma unroll
      for (int r = 0; r < 4; ++r) {
        float pv = __builtin_amdgcn_exp2f(s[jt][r] - mrow[r]);
        rs_acc[r] += pv;  // per-lane partial; reduced once at the end
        int iw = w * 16 + g * 4 + r;
        int j = jt * 16 + l15;
        Ps[iw * 64 + (j ^ ((iw & 7) << 3))] = (bf16)pv;
      }
    }

    // O += P V   (Ps rows are wave-private: lgkmcnt ordering only, no barrier)
    __builtin_amdgcn_s_setprio(1);
#pragma unroll
    for (int ks2 = 0; ks2 < 2; ++ks2) {
      bf16x8 pa = *(const bf16x8*)(Ps + irow * 64 + (((ks2 * 4 + g) ^ (irow & 7)) << 3));
#pragma unroll
      for (int dt = 0; dt < 4; ++dt) {
        int drow = dt * 16 + l15;
        bf16x8 vb = *(const bf16x8*)(Vs[cur] + drow * 64 + (((ks2 * 4 + g) ^ (drow & 7)) << 3));
        oacc[dt] = mfma16(pa, vb, oacc[dt]);
      }
    }
    __builtin_amdgcn_s_setprio(0);

    __syncthreads();  // drains next-step staging + releases buf[cur] for reuse
  }

  // final l: reduce per-lane partials across the 16-lane row groups
  float lrow[4];
#pragma unroll
  for (int r = 0; r < 4; ++r) {
    float t2 = rs_acc[r];
    t2 += __shfl_xor(t2, 1);
    t2 += __shfl_xor(t2, 2);
    t2 += __shfl_xor(t2, 4);
    t2 += __shfl_xor(t2, 8);
    lrow[r] = t2;
  }

  // epilogue: UNNORMALIZED partial O (bf16) + m,l per row
  size_t zoff = (size_t)z * 16 * 2048;
#pragma unroll
  for (int dt = 0; dt < 4; ++dt) {
#pragma unroll
    for (int r = 0; r < 4; ++r) {
      int i = w * 16 + g * 4 + r;
      Op[(zoff + (size_t)bh * 2048 + q0 + i) * 64 + dt * 16 + l15] =
          (bf16)oacc[dt][r];
    }
  }
  if (l15 == 0) {
#pragma unroll
    for (int r = 0; r < 4; ++r) {
      int i = w * 16 + g * 4 + r;
      mbuf[zoff + (size_t)bh * 2048 + q0 + i] = mrow[r];
      lbuf[zoff + (size_t)bh * 2048 + q0 + i] = lrow[r];
    }
  }
}

// ---------------------------------------------------------------------------
// combine: oh[row][d] = (w0*O0 + w1*O1) / (w0*l0 + w1*l1), w_z = 2^(m_z - M)
// 131072 threads: thread = (row, 16-d chunk). grid 512, block 256.
// ---------------------------------------------------------------------------
__global__ __launch_bounds__(256) void combine(
    const bf16* __restrict__ Op, const float* __restrict__ mbuf,
    const float* __restrict__ lbuf, bf16* __restrict__ oh) {
  int idx = blockIdx.x * 256 + threadIdx.x;
  int row = idx >> 2;
  int dc = (idx & 3) * 16;
  float m0 = mbuf[row], m1 = mbuf[32768 + row];
  float l0 = lbuf[row], l1 = lbuf[32768 + row];
  float M = fmaxf(m0, m1);
  float w0 = __builtin_amdgcn_exp2f(m0 - M);
  float w1 = __builtin_amdgcn_exp2f(m1 - M);
  float invL = 1.0f / (w0 * l0 + w1 * l1);
  float a0 = w0 * invL, a1 = w1 * invL;

  const bf16x8* p0 = (const bf16x8*)(Op + (size_t)row * 64 + dc);
  const bf16x8* p1 = (const bf16x8*)(Op + (size_t)32768 * 64 + (size_t)row * 64 + dc);
  bf16x8* po = (bf16x8*)(oh + (size_t)row * 64 + dc);
#pragma unroll
  for (int v = 0; v < 2; ++v) {
    bf16x8 x0 = p0[v], x1 = p1[v];
    bf16x8 o;
#pragma unroll
    for (int e = 0; e < 8; ++e)
      o[e] = (bf16)(a0 * (float)x0[e] + a1 * (float)x1[e]);
    po[v] = o;
  }
}

// ---------------------------------------------------------------------------
// out_gemm: out[b][r][p] = sum_k Wor[r][k] * oh_as_B[p][k] + bo[r]   (fp32 out)
// grid (4, 16, 2)
// ---------------------------------------------------------------------------
__global__ __launch_bounds__(256) void out_gemm(
    const bf16* __restrict__ Wor, const bf16* __restrict__ oh,
    const float* __restrict__ bo, float* __restrict__ out) {
  __shared__ bf16 Al[128 * 32];
  __shared__ bf16 Bl[128 * 32];
  int b = blockIdx.z;
  int r0 = blockIdx.x * 128;
  int p0 = blockIdx.y * 128;
  int tid = threadIdx.x, w = tid >> 6, lane = tid & 63;
  int wm = w >> 1, wn = w & 1;
  int g = lane >> 4, l15 = lane & 15;

  const bf16* Abase = Wor + (size_t)r0 * 512;

  f32x4 acc[4][4] = {};

  for (int ks = 0; ks < 16; ++ks) {
    int k0 = ks * 32;
    int hh = k0 >> 6, d0 = k0 & 63;
    const bf16* Bbase = oh + (((size_t)b * 8 + hh) * 2048 + p0) * 64 + d0;
    __syncthreads();
#pragma unroll
    for (int i = 0; i < 2; ++i) {
      int rowl = w * 32 + i * 16 + (lane >> 2);
      int ch = lane & 3;
      gload_lds16(Abase + (size_t)rowl * 512 + k0 + ch * 8,
                  Al + (w * 32 + i * 16) * 32);
      gload_lds16(Bbase + (size_t)rowl * 64 + ch * 8,
                  Bl + (w * 32 + i * 16) * 32);
    }
    __syncthreads();
    bf16x8 a[4], bb[4];
#pragma unroll
    for (int mi = 0; mi < 4; ++mi)
      a[mi] = *(const bf16x8*)(Al + (wm * 64 + mi * 16 + l15) * 32 + g * 8);
#pragma unroll
    for (int ni = 0; ni < 4; ++ni)
      bb[ni] = *(const bf16x8*)(Bl + (wn * 64 + ni * 16 + l15) * 32 + g * 8);
#pragma unroll
    for (int mi = 0; mi < 4; ++mi)
#pragma unroll
      for (int ni = 0; ni < 4; ++ni)
        acc[mi][ni] = mfma16(a[mi], bb[ni], acc[mi][ni]);
  }

#pragma unroll
  for (int mi = 0; mi < 4; ++mi) {
#pragma unroll
    for (int ni = 0; ni < 4; ++ni) {
#pragma unroll
      for (int r = 0; r < 4; ++r) {
        int row = r0 + wm * 64 + mi * 16 + g * 4 + r;
        int p = p0 + wn * 64 + ni * 16 + l15;
        out[((size_t)b * 512 + row) * 2048 + p] = acc[mi][ni][r] + bo[row];
      }
    }
  }
}

// ---------------------------------------------------------------------------
extern "C" void kernel_launch(void* const* d_in, const int* in_sizes, int n_in,
                              void* d_out, int out_size, void* d_ws, size_t ws_size,
                              hipStream_t stream) {
  (void)in_sizes; (void)n_in; (void)out_size; (void)ws_size;
  const float* Q  = (const float*)d_in[0];
  const float* Wq = (const float*)d_in[1];
  const float* bq = (const float*)d_in[2];
  const float* Wk = (const float*)d_in[3];
  const float* bk = (const float*)d_in[4];
  const float* Wv = (const float*)d_in[5];
  const float* bv = (const float*)d_in[6];
  const float* Wo = (const float*)d_in[7];
  const float* bo = (const float*)d_in[8];
  float* out = (float*)d_out;

  char* ws = (char*)d_ws;
  bf16*  Wf    = (bf16*)(ws + 0);          // 1536*512*2  = 1572864
  bf16*  Wor   = (bf16*)(ws + 1572864);    // 512*512*2   = 524288
  float* biasf = (float*)(ws + 2097152);   // 1536*4      = 6144
  bf16*  Qt    = (bf16*)(ws + 2103296);    // 2*2048*512*2 = 4194304
  bf16*  qp    = (bf16*)(ws + 6297600);    // 4194304
  bf16*  kp    = (bf16*)(ws + 10491904);   // 4194304
  bf16*  vn    = (bf16*)(ws + 14686208);   // 4194304
  bf16*  oh    = (bf16*)(ws + 18880512);   // 4194304  (ends 23074816)
  bf16*  Opart = (bf16*)(ws + 23074816);   // 2*16*2048*64*2 = 8388608
  float* mbuf  = (float*)(ws + 31463424);  // 2*16*2048*4 = 262144
  float* lbuf  = (float*)(ws + 31725568);  // 262144 (ends ~32.0 MB)

  prep_w<<<dim3(2048), dim3(256), 0, stream>>>(Wq, bq, Wk, bk, Wv, bv, Wo,
                                               Wf, biasf, Wor);
  prep_qt<<<dim3(32, 8, 2), dim3(256), 0, stream>>>(Q, Qt);
  qkv_gemm<<<dim3(12, 16, 2), dim3(256), 0, stream>>>(Wf, Qt, biasf, qp, kp, vn);
  attn_k<<<dim3(16, 16, 2), dim3(512), 0, stream>>>(qp, kp, vn, Opart, mbuf, lbuf);
  combine<<<dim3(512), dim3(256), 0, stream>>>(Opart, mbuf, lbuf, oh);
  out_gemm<<<dim3(4, 16, 2), dim3(256), 0, stream>>>(Wor, oh, bo, out);
}

// Round 5
// 89.207 us; speedup vs baseline: 1.2908x; 1.1190x over previous
//
#include <hip/hip_runtime.h>

#define DEV __device__ __forceinline__

typedef __bf16 bf16;
typedef __bf16 bf16x8 __attribute__((ext_vector_type(8)));
typedef float f32x4 __attribute__((ext_vector_type(4)));

#define B_ 2
#define D_ 512
#define N_ 2048
#define H_ 8
#define MD_ 64
// 1/sqrt(512) * log2(e): scores pre-scaled so softmax uses exp2 directly
#define SCALE_F (0.04419417382415922f * 1.4426950408889634f)

DEV void gload_lds16(const void* g, void* l) {
  __builtin_amdgcn_global_load_lds(
      (const __attribute__((address_space(1))) void*)g,
      (__attribute__((address_space(3))) void*)l, 16, 0, 0);
}

DEV f32x4 mfma16(bf16x8 a, bf16x8 b, f32x4 c) {
  return __builtin_amdgcn_mfma_f32_16x16x32_bf16(a, b, c, 0, 0, 0);
}

// ---------------------------------------------------------------------------
// prep_w: rows 0..1535 -> Wf bf16 (Wq*SCALE | Wk | Wv), bias_f (bq*SCALE|bk|bv)
//         rows 1536..2047 -> Wo_r[r][h*64+d] = Wo[r][d*8+h]  (bf16)
// ---------------------------------------------------------------------------
__global__ __launch_bounds__(256) void prep_w(
    const float* __restrict__ Wq, const float* __restrict__ bq,
    const float* __restrict__ Wk, const float* __restrict__ bk,
    const float* __restrict__ Wv, const float* __restrict__ bv,
    const float* __restrict__ Wo,
    bf16* __restrict__ Wf, float* __restrict__ biasf, bf16* __restrict__ Wor) {
  int row = blockIdx.x;
  int t = threadIdx.x;
  if (row < 1536) {
    const float* src;
    float scale = 1.0f;
    if (row < 512)       { src = Wq + (size_t)row * 512; scale = SCALE_F; }
    else if (row < 1024) { src = Wk + (size_t)(row - 512) * 512; }
    else                 { src = Wv + (size_t)(row - 1024) * 512; }
    for (int c = t; c < 512; c += 256)
      Wf[(size_t)row * 512 + c] = (bf16)(src[c] * scale);
    if (t == 0) {
      float bb;
      if (row < 512)       bb = bq[row] * SCALE_F;
      else if (row < 1024) bb = bk[row - 512];
      else                 bb = bv[row - 1024];
      biasf[row] = bb;
    }
  } else {
    int r = row - 1536;
    for (int c2 = t; c2 < 512; c2 += 256) {
      int hh = c2 >> 6, dd = c2 & 63;
      Wor[(size_t)r * 512 + c2] = (bf16)Wo[(size_t)r * 512 + dd * 8 + hh];
    }
  }
}

// ---------------------------------------------------------------------------
// prep_qt: Qt[b][n][c] = bf16(Q[b][c][n])   (64x64 tiles through LDS)
// grid (N/64, D/64, B), block 256
// ---------------------------------------------------------------------------
__global__ __launch_bounds__(256) void prep_qt(const float* __restrict__ Q,
                                               bf16* __restrict__ Qt) {
  __shared__ float tile[64][65];
  int b = blockIdx.z;
  int d0 = blockIdx.y * 64;
  int n0 = blockIdx.x * 64;
  int t = threadIdx.x;
  int r = t >> 2, cw = t & 3;

  const float* src = Q + ((size_t)(b * 512 + d0 + r)) * 2048 + n0 + cw * 16;
#pragma unroll
  for (int e4 = 0; e4 < 4; ++e4) {
    float4 v = *(const float4*)(src + e4 * 4);
    tile[r][cw * 16 + e4 * 4 + 0] = v.x;
    tile[r][cw * 16 + e4 * 4 + 1] = v.y;
    tile[r][cw * 16 + e4 * 4 + 2] = v.z;
    tile[r][cw * 16 + e4 * 4 + 3] = v.w;
  }
  __syncthreads();
  bf16x8 o0{}, o1{};
#pragma unroll
  for (int e = 0; e < 8; ++e) {
    o0[e] = (bf16)tile[cw * 16 + e][r];
    o1[e] = (bf16)tile[cw * 16 + 8 + e][r];
  }
  bf16* dst = Qt + ((size_t)(b * 2048 + n0 + r)) * 512 + d0 + cw * 16;
  *(bf16x8*)dst = o0;
  *((bf16x8*)dst + 1) = o1;
}

// ---------------------------------------------------------------------------
// qkv_gemm: C[c][p] = sum_k Wf[c][k] * Qt[b][p][k] + bias[c]
// 128x128 tile, BK=32, 4 waves (2x2), 4x4 frags/wave, global_load_lds staging.
// Epilogue: c<512 -> qp[b][h][p][d]; c<1024 -> kp; else vn[b][c][p]
// grid (12, 16, 2)
// ---------------------------------------------------------------------------
__global__ __launch_bounds__(256) void qkv_gemm(
    const bf16* __restrict__ Wf, const bf16* __restrict__ Qt,
    const float* __restrict__ biasf,
    bf16* __restrict__ qp, bf16* __restrict__ kp, bf16* __restrict__ vn) {
  __shared__ bf16 Al[128 * 32];
  __shared__ bf16 Bl[128 * 32];
  int b = blockIdx.z;
  int c0 = blockIdx.x * 128;
  int p0 = blockIdx.y * 128;
  int tid = threadIdx.x, w = tid >> 6, lane = tid & 63;
  int wm = w >> 1, wn = w & 1;
  int g = lane >> 4, l15 = lane & 15;

  const bf16* Abase = Wf + (size_t)c0 * 512;
  const bf16* Bbase = Qt + ((size_t)b * 2048 + p0) * 512;

  f32x4 acc[4][4] = {};

  for (int ks = 0; ks < 16; ++ks) {
    int k0 = ks * 32;
    __syncthreads();
#pragma unroll
    for (int i = 0; i < 2; ++i) {
      int rowl = w * 32 + i * 16 + (lane >> 2);
      int ch = lane & 3;
      gload_lds16(Abase + (size_t)rowl * 512 + k0 + ch * 8,
                  Al + (w * 32 + i * 16) * 32);
      gload_lds16(Bbase + (size_t)rowl * 512 + k0 + ch * 8,
                  Bl + (w * 32 + i * 16) * 32);
    }
    __syncthreads();
    bf16x8 a[4], bb[4];
#pragma unroll
    for (int mi = 0; mi < 4; ++mi)
      a[mi] = *(const bf16x8*)(Al + (wm * 64 + mi * 16 + l15) * 32 + g * 8);
#pragma unroll
    for (int ni = 0; ni < 4; ++ni)
      bb[ni] = *(const bf16x8*)(Bl + (wn * 64 + ni * 16 + l15) * 32 + g * 8);
#pragma unroll
    for (int mi = 0; mi < 4; ++mi)
#pragma unroll
      for (int ni = 0; ni < 4; ++ni)
        acc[mi][ni] = mfma16(a[mi], bb[ni], acc[mi][ni]);
  }

#pragma unroll
  for (int mi = 0; mi < 4; ++mi) {
#pragma unroll
    for (int ni = 0; ni < 4; ++ni) {
#pragma unroll
      for (int r = 0; r < 4; ++r) {
        int row = c0 + wm * 64 + mi * 16 + g * 4 + r;
        int p = p0 + wn * 64 + ni * 16 + l15;
        float val = acc[mi][ni][r] + biasf[row];
        bf16 hv = (bf16)val;
        if (row < 512) {
          int c = row;
          qp[(((size_t)b * 8 + (c & 7)) * 2048 + p) * 64 + (c >> 3)] = hv;
        } else if (row < 1024) {
          int c = row - 512;
          kp[(((size_t)b * 8 + (c & 7)) * 2048 + p) * 64 + (c >> 3)] = hv;
        } else {
          int c = row - 1024;
          vn[((size_t)b * 512 + c) * 2048 + p] = hv;
        }
      }
    }
  }
}

// ---------------------------------------------------------------------------
// attn_k v5: QBLK=128, 8 waves (512 thr), KV-split x2. grid (16, 16, 2).
// Fast-path softmax: per-lane 16-value max vs min(mrow)+8 (no shuffles);
// exact shuffle-reduced max + rescale only when the guard fires (step 0 +
// rarely after). Q in regs; K/V dbuf; 1 barrier/step; setprio on MFMA.
// Writes unnormalized O-partial (bf16) + per-row m,l (f32, log2 domain).
// ---------------------------------------------------------------------------
__global__ __launch_bounds__(512) void attn_k(
    const bf16* __restrict__ qp, const bf16* __restrict__ kp,
    const bf16* __restrict__ vn, bf16* __restrict__ Op,
    float* __restrict__ mbuf, float* __restrict__ lbuf) {
  __shared__ bf16 Ks[2][64 * 64];
  __shared__ bf16 Vs[2][64 * 64];
  __shared__ bf16 Ps[128 * 64];
  int q0 = blockIdx.x * 128;
  int bh = blockIdx.y;            // b*8 + h
  int z = blockIdx.z;             // kv split
  int b = bh >> 3, h = bh & 7;
  int tid = threadIdx.x, w = tid >> 6, lane = tid & 63;
  int g = lane >> 4, l15 = lane & 15;
  int irow = w * 16 + l15;        // this wave's q-row for MFMA A/C (0..127)

  // Q A-fragments straight to registers (reused all 16 steps)
  bf16x8 qreg[2];
#pragma unroll
  for (int ks2 = 0; ks2 < 2; ++ks2)
    qreg[ks2] = *(const bf16x8*)(qp + ((size_t)bh * 2048 + q0 + irow) * 64 +
                                 ks2 * 32 + g * 8);

  // staging coords: 512 lanes cover one 64x64 bf16 tile (8KB) in ONE
  // gload_lds16 per wave. row = tid>>3, swizzled source chunk, linear dest.
  int krow = tid >> 3;
  int kch = (tid & 7) ^ (krow & 7);

  const bf16* Kall = kp + (size_t)bh * 2048 * 64 + (size_t)z * 16 * 64 * 64;
  const bf16* Vall = vn + ((size_t)(b * 512 + h)) * 2048 + (size_t)z * 16 * 64;

  // stage K/V local step 0 into buffer 0
  gload_lds16(Kall + (size_t)krow * 64 + kch * 8, Ks[0] + w * 512);
  gload_lds16(Vall + (size_t)krow * 16384 + kch * 8, Vs[0] + w * 512);

  f32x4 oacc[4] = {};
  float mrow[4], rs_acc[4];
#pragma unroll
  for (int r = 0; r < 4; ++r) { mrow[r] = -1e30f; rs_acc[r] = 0.0f; }

  __syncthreads();  // step-0 staging drained (vmcnt(0) inside)

  for (int t = 0; t < 16; ++t) {
    int cur = t & 1, nxt = cur ^ 1;
    int tn = (t < 15) ? t + 1 : 15;  // clamp (redundant last prefetch)

    // issue next-step staging (lands during compute; drained at loop-end sync)
    gload_lds16(Kall + (size_t)tn * 64 * 64 + (size_t)krow * 64 + kch * 8,
                Ks[nxt] + w * 512);
    gload_lds16(Vall + (size_t)tn * 64 + (size_t)krow * 16384 + kch * 8,
                Vs[nxt] + w * 512);

    // S = Q K^T for this wave's 16-row strip
    f32x4 s[4] = {};
    __builtin_amdgcn_s_setprio(1);
#pragma unroll
    for (int ks2 = 0; ks2 < 2; ++ks2) {
#pragma unroll
      for (int jt = 0; jt < 4; ++jt) {
        int jrow = jt * 16 + l15;
        bf16x8 kb = *(const bf16x8*)(Ks[cur] + jrow * 64 + (((ks2 * 4 + g) ^ (jrow & 7)) << 3));
        s[jt] = mfma16(qreg[ks2], kb, s[jt]);
      }
    }
    __builtin_amdgcn_s_setprio(0);

    // fast defer-max guard: per-lane max (no cross-lane), wave-uniform branch
    float lm = s[0][0];
#pragma unroll
    for (int jt = 0; jt < 4; ++jt)
#pragma unroll
      for (int r = 0; r < 4; ++r) lm = fmaxf(lm, s[jt][r]);
    float mmin = fminf(fminf(mrow[0], mrow[1]), fminf(mrow[2], mrow[3]));
    if (__any(lm > mmin + 8.0f)) {
      // exact per-row shuffle-reduced max + rescale (step 0 + rare)
#pragma unroll
      for (int r = 0; r < 4; ++r) {
        float rm = fmaxf(fmaxf(s[0][r], s[1][r]), fmaxf(s[2][r], s[3][r]));
        rm = fmaxf(rm, __shfl_xor(rm, 1));
        rm = fmaxf(rm, __shfl_xor(rm, 2));
        rm = fmaxf(rm, __shfl_xor(rm, 4));
        rm = fmaxf(rm, __shfl_xor(rm, 8));
        float nm = fmaxf(mrow[r], rm);
        float esc = __builtin_amdgcn_exp2f(mrow[r] - nm);
        mrow[r] = nm;
        rs_acc[r] *= esc;
#pragma unroll
        for (int dt = 0; dt < 4; ++dt) oacc[dt][r] *= esc;
      }
    }

    // P = exp2(S - m), accumulate per-lane l partials, store P to LDS
#pragma unroll
    for (int jt = 0; jt < 4; ++jt) {
#pragma unroll
      for (int r = 0; r < 4; ++r) {
        float pv = __builtin_amdgcn_exp2f(s[jt][r] - mrow[r]);
        rs_acc[r] += pv;
        int iw = w * 16 + g * 4 + r;
        int j = jt * 16 + l15;
        Ps[iw * 64 + (j ^ ((iw & 7) << 3))] = (bf16)pv;
      }
    }

    // O += P V   (Ps rows are wave-private: lgkmcnt ordering only, no barrier)
    __builtin_amdgcn_s_setprio(1);
#pragma unroll
    for (int ks2 = 0; ks2 < 2; ++ks2) {
      bf16x8 pa = *(const bf16x8*)(Ps + irow * 64 + (((ks2 * 4 + g) ^ (irow & 7)) << 3));
#pragma unroll
      for (int dt = 0; dt < 4; ++dt) {
        int drow = dt * 16 + l15;
        bf16x8 vb = *(const bf16x8*)(Vs[cur] + drow * 64 + (((ks2 * 4 + g) ^ (drow & 7)) << 3));
        oacc[dt] = mfma16(pa, vb, oacc[dt]);
      }
    }
    __builtin_amdgcn_s_setprio(0);

    __syncthreads();  // drains next-step staging + releases buf[cur] for reuse
  }

  // final l: reduce per-lane partials across the 16-lane row groups
  float lrow[4];
#pragma unroll
  for (int r = 0; r < 4; ++r) {
    float t2 = rs_acc[r];
    t2 += __shfl_xor(t2, 1);
    t2 += __shfl_xor(t2, 2);
    t2 += __shfl_xor(t2, 4);
    t2 += __shfl_xor(t2, 8);
    lrow[r] = t2;
  }

  // epilogue: UNNORMALIZED partial O (bf16) + m,l per row
  size_t zoff = (size_t)z * 16 * 2048;
#pragma unroll
  for (int dt = 0; dt < 4; ++dt) {
#pragma unroll
    for (int r = 0; r < 4; ++r) {
      int i = w * 16 + g * 4 + r;
      Op[(zoff + (size_t)bh * 2048 + q0 + i) * 64 + dt * 16 + l15] =
          (bf16)oacc[dt][r];
    }
  }
  if (l15 == 0) {
#pragma unroll
    for (int r = 0; r < 4; ++r) {
      int i = w * 16 + g * 4 + r;
      mbuf[zoff + (size_t)bh * 2048 + q0 + i] = mrow[r];
      lbuf[zoff + (size_t)bh * 2048 + q0 + i] = lrow[r];
    }
  }
}

// ---------------------------------------------------------------------------
// combine: oh[row][d] = (w0*O0 + w1*O1) / (w0*l0 + w1*l1), w_z = 2^(m_z - M)
// 131072 threads: thread = (row, 16-d chunk). grid 512, block 256.
// ---------------------------------------------------------------------------
__global__ __launch_bounds__(256) void combine(
    const bf16* __restrict__ Op, const float* __restrict__ mbuf,
    const float* __restrict__ lbuf, bf16* __restrict__ oh) {
  int idx = blockIdx.x * 256 + threadIdx.x;
  int row = idx >> 2;
  int dc = (idx & 3) * 16;
  float m0 = mbuf[row], m1 = mbuf[32768 + row];
  float l0 = lbuf[row], l1 = lbuf[32768 + row];
  float M = fmaxf(m0, m1);
  float w0 = __builtin_amdgcn_exp2f(m0 - M);
  float w1 = __builtin_amdgcn_exp2f(m1 - M);
  float invL = 1.0f / (w0 * l0 + w1 * l1);
  float a0 = w0 * invL, a1 = w1 * invL;

  const bf16x8* p0 = (const bf16x8*)(Op + (size_t)row * 64 + dc);
  const bf16x8* p1 = (const bf16x8*)(Op + (size_t)32768 * 64 + (size_t)row * 64 + dc);
  bf16x8* po = (bf16x8*)(oh + (size_t)row * 64 + dc);
#pragma unroll
  for (int v = 0; v < 2; ++v) {
    bf16x8 x0 = p0[v], x1 = p1[v];
    bf16x8 o;
#pragma unroll
    for (int e = 0; e < 8; ++e)
      o[e] = (bf16)(a0 * (float)x0[e] + a1 * (float)x1[e]);
    po[v] = o;
  }
}

// ---------------------------------------------------------------------------
// out_gemm v2: 128x64 tiles -> grid (4, 32, 2) = 256 blocks (all CUs).
// 4 waves as 2x2 (wave = 64r x 32p, 4x2 frags). BK=32.
// out[b][r][p] = sum_k Wor[r][k] * oh_as_B[p][k] + bo[r]   (fp32 out)
// ---------------------------------------------------------------------------
__global__ __launch_bounds__(256) void out_gemm(
    const bf16* __restrict__ Wor, const bf16* __restrict__ oh,
    const float* __restrict__ bo, float* __restrict__ out) {
  __shared__ bf16 Al[128 * 32];
  __shared__ bf16 Bl[64 * 32];
  int b = blockIdx.z;
  int r0 = blockIdx.x * 128;
  int p0 = blockIdx.y * 64;
  int tid = threadIdx.x, w = tid >> 6, lane = tid & 63;
  int wm = w >> 1, wn = w & 1;
  int g = lane >> 4, l15 = lane & 15;

  const bf16* Abase = Wor + (size_t)r0 * 512;

  f32x4 acc[4][2] = {};

  for (int ks = 0; ks < 16; ++ks) {
    int k0 = ks * 32;
    int hh = k0 >> 6, d0 = k0 & 63;
    const bf16* Bbase = oh + (((size_t)b * 8 + hh) * 2048 + p0) * 64 + d0;
    __syncthreads();
#pragma unroll
    for (int i = 0; i < 2; ++i) {
      int rowl = w * 32 + i * 16 + (lane >> 2);
      gload_lds16(Abase + (size_t)rowl * 512 + k0 + (lane & 3) * 8,
                  Al + (w * 32 + i * 16) * 32);
    }
    {
      int browl = w * 16 + (lane >> 2);
      gload_lds16(Bbase + (size_t)browl * 64 + (lane & 3) * 8,
                  Bl + w * 16 * 32);
    }
    __syncthreads();
    bf16x8 a[4], bb[2];
#pragma unroll
    for (int mi = 0; mi < 4; ++mi)
      a[mi] = *(const bf16x8*)(Al + (wm * 64 + mi * 16 + l15) * 32 + g * 8);
#pragma unroll
    for (int ni = 0; ni < 2; ++ni)
      bb[ni] = *(const bf16x8*)(Bl + (wn * 32 + ni * 16 + l15) * 32 + g * 8);
#pragma unroll
    for (int mi = 0; mi < 4; ++mi)
#pragma unroll
      for (int ni = 0; ni < 2; ++ni)
        acc[mi][ni] = mfma16(a[mi], bb[ni], acc[mi][ni]);
  }

#pragma unroll
  for (int mi = 0; mi < 4; ++mi) {
#pragma unroll
    for (int ni = 0; ni < 2; ++ni) {
#pragma unroll
      for (int r = 0; r < 4; ++r) {
        int row = r0 + wm * 64 + mi * 16 + g * 4 + r;
        int p = p0 + wn * 32 + ni * 16 + l15;
        out[((size_t)b * 512 + row) * 2048 + p] = acc[mi][ni][r] + bo[row];
      }
    }
  }
}

// ---------------------------------------------------------------------------
extern "C" void kernel_launch(void* const* d_in, const int* in_sizes, int n_in,
                              void* d_out, int out_size, void* d_ws, size_t ws_size,
                              hipStream_t stream) {
  (void)in_sizes; (void)n_in; (void)out_size; (void)ws_size;
  const float* Q  = (const float*)d_in[0];
  const float* Wq = (const float*)d_in[1];
  const float* bq = (const float*)d_in[2];
  const float* Wk = (const float*)d_in[3];
  const float* bk = (const float*)d_in[4];
  const float* Wv = (const float*)d_in[5];
  const float* bv = (const float*)d_in[6];
  const float* Wo = (const float*)d_in[7];
  const float* bo = (const float*)d_in[8];
  float* out = (float*)d_out;

  char* ws = (char*)d_ws;
  bf16*  Wf    = (bf16*)(ws + 0);          // 1536*512*2  = 1572864
  bf16*  Wor   = (bf16*)(ws + 1572864);    // 512*512*2   = 524288
  float* biasf = (float*)(ws + 2097152);   // 1536*4      = 6144
  bf16*  Qt    = (bf16*)(ws + 2103296);    // 2*2048*512*2 = 4194304
  bf16*  qp    = (bf16*)(ws + 6297600);    // 4194304
  bf16*  kp    = (bf16*)(ws + 10491904);   // 4194304
  bf16*  vn    = (bf16*)(ws + 14686208);   // 4194304
  bf16*  oh    = (bf16*)(ws + 18880512);   // 4194304  (ends 23074816)
  bf16*  Opart = (bf16*)(ws + 23074816);   // 2*16*2048*64*2 = 8388608
  float* mbuf  = (float*)(ws + 31463424);  // 2*16*2048*4 = 262144
  float* lbuf  = (float*)(ws + 31725568);  // 262144 (ends ~32.0 MB)

  prep_w<<<dim3(2048), dim3(256), 0, stream>>>(Wq, bq, Wk, bk, Wv, bv, Wo,
                                               Wf, biasf, Wor);
  prep_qt<<<dim3(32, 8, 2), dim3(256), 0, stream>>>(Q, Qt);
  qkv_gemm<<<dim3(12, 16, 2), dim3(256), 0, stream>>>(Wf, Qt, biasf, qp, kp, vn);
  attn_k<<<dim3(16, 16, 2), dim3(512), 0, stream>>>(qp, kp, vn, Opart, mbuf, lbuf);
  combine<<<dim3(512), dim3(256), 0, stream>>>(Opart, mbuf, lbuf, oh);
  out_gemm<<<dim3(4, 32, 2), dim3(256), 0, stream>>>(Wor, oh, bo, out);
}

// Round 6
// 81.922 us; speedup vs baseline: 1.4056x; 1.0889x over previous
//
#include <hip/hip_runtime.h>

#define DEV __device__ __forceinline__

typedef __bf16 bf16;
typedef __bf16 bf16x8 __attribute__((ext_vector_type(8)));
typedef __bf16 bf16x4 __attribute__((ext_vector_type(4)));
typedef float f32x4 __attribute__((ext_vector_type(4)));

#define B_ 2
#define D_ 512
#define N_ 2048
#define H_ 8
#define MD_ 64
// 1/sqrt(512) * log2(e): scores pre-scaled so softmax uses exp2 directly
#define SCALE_F (0.04419417382415922f * 1.4426950408889634f)

DEV void gload_lds16(const void* g, void* l) {
  __builtin_amdgcn_global_load_lds(
      (const __attribute__((address_space(1))) void*)g,
      (__attribute__((address_space(3))) void*)l, 16, 0, 0);
}

DEV f32x4 mfma16(bf16x8 a, bf16x8 b, f32x4 c) {
  return __builtin_amdgcn_mfma_f32_16x16x32_bf16(a, b, c, 0, 0, 0);
}

// ---------------------------------------------------------------------------
// prep_w: rows 0..1535 -> Wf bf16 (Wq*SCALE | Wk | Wv), bias_f (bq*SCALE|bk|bv)
//         rows 1536..2047 -> Wo_r[r][h*64+d] = Wo[r][d*8+h]  (bf16)
// ---------------------------------------------------------------------------
__global__ __launch_bounds__(256) void prep_w(
    const float* __restrict__ Wq, const float* __restrict__ bq,
    const float* __restrict__ Wk, const float* __restrict__ bk,
    const float* __restrict__ Wv, const float* __restrict__ bv,
    const float* __restrict__ Wo,
    bf16* __restrict__ Wf, float* __restrict__ biasf, bf16* __restrict__ Wor) {
  int row = blockIdx.x;
  int t = threadIdx.x;
  if (row < 1536) {
    const float* src;
    float scale = 1.0f;
    if (row < 512)       { src = Wq + (size_t)row * 512; scale = SCALE_F; }
    else if (row < 1024) { src = Wk + (size_t)(row - 512) * 512; }
    else                 { src = Wv + (size_t)(row - 1024) * 512; }
    for (int c = t; c < 512; c += 256)
      Wf[(size_t)row * 512 + c] = (bf16)(src[c] * scale);
    if (t == 0) {
      float bb;
      if (row < 512)       bb = bq[row] * SCALE_F;
      else if (row < 1024) bb = bk[row - 512];
      else                 bb = bv[row - 1024];
      biasf[row] = bb;
    }
  } else {
    int r = row - 1536;
    for (int c2 = t; c2 < 512; c2 += 256) {
      int hh = c2 >> 6, dd = c2 & 63;
      Wor[(size_t)r * 512 + c2] = (bf16)Wo[(size_t)r * 512 + dd * 8 + hh];
    }
  }
}

// ---------------------------------------------------------------------------
// prep_qt: Qt[b][n][c] = bf16(Q[b][c][n])   (64x64 tiles through LDS)
// grid (N/64, D/64, B), block 256
// ---------------------------------------------------------------------------
__global__ __launch_bounds__(256) void prep_qt(const float* __restrict__ Q,
                                               bf16* __restrict__ Qt) {
  __shared__ float tile[64][65];
  int b = blockIdx.z;
  int d0 = blockIdx.y * 64;
  int n0 = blockIdx.x * 64;
  int t = threadIdx.x;
  int r = t >> 2, cw = t & 3;

  const float* src = Q + ((size_t)(b * 512 + d0 + r)) * 2048 + n0 + cw * 16;
#pragma unroll
  for (int e4 = 0; e4 < 4; ++e4) {
    float4 v = *(const float4*)(src + e4 * 4);
    tile[r][cw * 16 + e4 * 4 + 0] = v.x;
    tile[r][cw * 16 + e4 * 4 + 1] = v.y;
    tile[r][cw * 16 + e4 * 4 + 2] = v.z;
    tile[r][cw * 16 + e4 * 4 + 3] = v.w;
  }
  __syncthreads();
  bf16x8 o0{}, o1{};
#pragma unroll
  for (int e = 0; e < 8; ++e) {
    o0[e] = (bf16)tile[cw * 16 + e][r];
    o1[e] = (bf16)tile[cw * 16 + 8 + e][r];
  }
  bf16* dst = Qt + ((size_t)(b * 2048 + n0 + r)) * 512 + d0 + cw * 16;
  *(bf16x8*)dst = o0;
  *((bf16x8*)dst + 1) = o1;
}

// ---------------------------------------------------------------------------
// qkv_gemm v2: 128x64 tiles -> grid (12, 32, 2) = 768 blocks = 3/CU even.
// C[c][p] = sum_k Wf[c][k] * Qt[b][p][k] + bias[c]
// 4 waves as 2x2 (wave = 64c x 32p, 4x2 frags). BK=32.
// Epilogue: c<512 -> qp[b][h][p][d]; c<1024 -> kp; else vn[b][c][p]
// ---------------------------------------------------------------------------
__global__ __launch_bounds__(256) void qkv_gemm(
    const bf16* __restrict__ Wf, const bf16* __restrict__ Qt,
    const float* __restrict__ biasf,
    bf16* __restrict__ qp, bf16* __restrict__ kp, bf16* __restrict__ vn) {
  __shared__ bf16 Al[128 * 32];
  __shared__ bf16 Bl[64 * 32];
  int b = blockIdx.z;
  int c0 = blockIdx.x * 128;
  int p0 = blockIdx.y * 64;
  int tid = threadIdx.x, w = tid >> 6, lane = tid & 63;
  int wm = w >> 1, wn = w & 1;
  int g = lane >> 4, l15 = lane & 15;

  const bf16* Abase = Wf + (size_t)c0 * 512;
  const bf16* Bbase = Qt + ((size_t)b * 2048 + p0) * 512;

  f32x4 acc[4][2] = {};

  for (int ks = 0; ks < 16; ++ks) {
    int k0 = ks * 32;
    __syncthreads();
#pragma unroll
    for (int i = 0; i < 2; ++i) {
      int rowl = w * 32 + i * 16 + (lane >> 2);
      gload_lds16(Abase + (size_t)rowl * 512 + k0 + (lane & 3) * 8,
                  Al + (w * 32 + i * 16) * 32);
    }
    {
      int browl = w * 16 + (lane >> 2);
      gload_lds16(Bbase + (size_t)browl * 512 + k0 + (lane & 3) * 8,
                  Bl + w * 16 * 32);
    }
    __syncthreads();
    bf16x8 a[4], bb[2];
#pragma unroll
    for (int mi = 0; mi < 4; ++mi)
      a[mi] = *(const bf16x8*)(Al + (wm * 64 + mi * 16 + l15) * 32 + g * 8);
#pragma unroll
    for (int ni = 0; ni < 2; ++ni)
      bb[ni] = *(const bf16x8*)(Bl + (wn * 32 + ni * 16 + l15) * 32 + g * 8);
#pragma unroll
    for (int mi = 0; mi < 4; ++mi)
#pragma unroll
      for (int ni = 0; ni < 2; ++ni)
        acc[mi][ni] = mfma16(a[mi], bb[ni], acc[mi][ni]);
  }

#pragma unroll
  for (int mi = 0; mi < 4; ++mi) {
#pragma unroll
    for (int ni = 0; ni < 2; ++ni) {
#pragma unroll
      for (int r = 0; r < 4; ++r) {
        int row = c0 + wm * 64 + mi * 16 + g * 4 + r;
        int p = p0 + wn * 32 + ni * 16 + l15;
        float val = acc[mi][ni][r] + biasf[row];
        bf16 hv = (bf16)val;
        if (row < 512) {
          int c = row;
          qp[(((size_t)b * 8 + (c & 7)) * 2048 + p) * 64 + (c >> 3)] = hv;
        } else if (row < 1024) {
          int c = row - 512;
          kp[(((size_t)b * 8 + (c & 7)) * 2048 + p) * 64 + (c >> 3)] = hv;
        } else {
          int c = row - 1024;
          vn[((size_t)b * 512 + c) * 2048 + p] = hv;
        }
      }
    }
  }
}

// ---------------------------------------------------------------------------
// attn_k v6: QBLK=128, 8 waves, KV-split x2. grid (16, 16, 2).
// SWAPPED QK^T: st[jt] = mfma(K_frag, Q_frag) = S^T, so each lane holds a
// 16-wide j-slice of ONE q-row (q = l15): row max = 15 in-lane fmax + 2
// shfl_xor; m/l are per-lane scalars; P-store is 4x ds_write_b64 (4
// consecutive j per jt). Rescale/normalize fetch per-acc-row values with 4
// __shfl (rare branch / epilogue only). K/V dbuf, 1 barrier/step, setprio.
// Writes unnormalized O-partial (bf16) + per-row m,l (f32, log2 domain).
// ---------------------------------------------------------------------------
__global__ __launch_bounds__(512) void attn_k(
    const bf16* __restrict__ qp, const bf16* __restrict__ kp,
    const bf16* __restrict__ vn, bf16* __restrict__ Op,
    float* __restrict__ mbuf, float* __restrict__ lbuf) {
  __shared__ bf16 Ks[2][64 * 64];
  __shared__ bf16 Vs[2][64 * 64];
  __shared__ bf16 Ps[128 * 64];
  int q0 = blockIdx.x * 128;
  int bh = blockIdx.y;            // b*8 + h
  int z = blockIdx.z;             // kv split
  int b = bh >> 3, h = bh & 7;
  int tid = threadIdx.x, w = tid >> 6, lane = tid & 63;
  int g = lane >> 4, l15 = lane & 15;
  int irow = w * 16 + l15;        // this lane's q-row (B-operand & Ps row)

  // Q B-fragments straight to registers (reused all 16 steps)
  bf16x8 qreg[2];
#pragma unroll
  for (int ks2 = 0; ks2 < 2; ++ks2)
    qreg[ks2] = *(const bf16x8*)(qp + ((size_t)bh * 2048 + q0 + irow) * 64 +
                                 ks2 * 32 + g * 8);

  // staging coords: 512 lanes cover one 64x64 bf16 tile (8KB) in ONE
  // gload_lds16 per wave. row = tid>>3, swizzled source chunk, linear dest.
  int krow = tid >> 3;
  int kch = (tid & 7) ^ (krow & 7);

  const bf16* Kall = kp + (size_t)bh * 2048 * 64 + (size_t)z * 16 * 64 * 64;
  const bf16* Vall = vn + ((size_t)(b * 512 + h)) * 2048 + (size_t)z * 16 * 64;

  // stage K/V local step 0 into buffer 0
  gload_lds16(Kall + (size_t)krow * 64 + kch * 8, Ks[0] + w * 512);
  gload_lds16(Vall + (size_t)krow * 16384 + kch * 8, Vs[0] + w * 512);

  f32x4 oacc[4] = {};
  float mrow = -1e30f, rs = 0.0f;  // per-lane: this lane's q-row (q = l15)

  __syncthreads();  // step-0 staging drained (vmcnt(0) inside)

  for (int t = 0; t < 16; ++t) {
    int cur = t & 1, nxt = cur ^ 1;
    int tn = (t < 15) ? t + 1 : 15;  // clamp (redundant last prefetch)

    // issue next-step staging (lands during compute; drained at loop-end sync)
    gload_lds16(Kall + (size_t)tn * 64 * 64 + (size_t)krow * 64 + kch * 8,
                Ks[nxt] + w * 512);
    gload_lds16(Vall + (size_t)tn * 64 + (size_t)krow * 16384 + kch * 8,
                Vs[nxt] + w * 512);

    // S^T = K Q^T : st[jt][i] = S[q = irow][j = jt*16 + g*4 + i]
    f32x4 st[4] = {};
    __builtin_amdgcn_s_setprio(1);
#pragma unroll
    for (int ks2 = 0; ks2 < 2; ++ks2) {
#pragma unroll
      for (int jt = 0; jt < 4; ++jt) {
        int jrow = jt * 16 + l15;
        bf16x8 kb = *(const bf16x8*)(Ks[cur] + jrow * 64 + (((ks2 * 4 + g) ^ (jrow & 7)) << 3));
        st[jt] = mfma16(kb, qreg[ks2], st[jt]);
      }
    }
    __builtin_amdgcn_s_setprio(0);

    // per-lane row max (15 fmax) + 2 shfl_xor across the 4 g-copies
    float rm = st[0][0];
#pragma unroll
    for (int jt = 0; jt < 4; ++jt)
#pragma unroll
      for (int i = 0; i < 4; ++i) rm = fmaxf(rm, st[jt][i]);
    rm = fmaxf(rm, __shfl_xor(rm, 16));
    rm = fmaxf(rm, __shfl_xor(rm, 32));

    if (__any(rm > mrow + 8.0f)) {   // defer-max guard (step 0 + rare)
      float nm = fmaxf(mrow, rm);
      float esc = __builtin_amdgcn_exp2f(mrow - nm);
      mrow = nm;
      rs *= esc;
#pragma unroll
      for (int r = 0; r < 4; ++r) {
        float er = __shfl(esc, g * 4 + r, 64);  // esc of acc row g*4+r
#pragma unroll
        for (int dt = 0; dt < 4; ++dt) oacc[dt][r] *= er;
      }
    }

    // P = exp2(S - m): 4 consecutive j per jt -> 4x ds_write_b64
#pragma unroll
    for (int jt = 0; jt < 4; ++jt) {
      bf16x4 pk;
#pragma unroll
      for (int i = 0; i < 4; ++i) {
        float pv = __builtin_amdgcn_exp2f(st[jt][i] - mrow);
        rs += pv;
        pk[i] = (bf16)pv;
      }
      int j0 = jt * 16 + g * 4;
      *(bf16x4*)(Ps + irow * 64 + (j0 ^ ((irow & 7) << 3))) = pk;
    }

    // O += P V   (Ps rows are wave-private: lgkmcnt ordering only, no barrier)
    __builtin_amdgcn_s_setprio(1);
#pragma unroll
    for (int ks2 = 0; ks2 < 2; ++ks2) {
      bf16x8 pa = *(const bf16x8*)(Ps + irow * 64 + (((ks2 * 4 + g) ^ (irow & 7)) << 3));
#pragma unroll
      for (int dt = 0; dt < 4; ++dt) {
        int drow = dt * 16 + l15;
        bf16x8 vb = *(const bf16x8*)(Vs[cur] + drow * 64 + (((ks2 * 4 + g) ^ (drow & 7)) << 3));
        oacc[dt] = mfma16(pa, vb, oacc[dt]);
      }
    }
    __builtin_amdgcn_s_setprio(0);

    __syncthreads();  // drains next-step staging + releases buf[cur] for reuse
  }

  // full row sum (combine the 4 g-copies)
  rs += __shfl_xor(rs, 16);
  rs += __shfl_xor(rs, 32);

  // epilogue: UNNORMALIZED partial O (bf16) + m,l per row
  size_t zoff = (size_t)z * 16 * 2048;
#pragma unroll
  for (int dt = 0; dt < 4; ++dt) {
#pragma unroll
    for (int r = 0; r < 4; ++r) {
      int i = w * 16 + g * 4 + r;
      Op[(zoff + (size_t)bh * 2048 + q0 + i) * 64 + dt * 16 + l15] =
          (bf16)oacc[dt][r];
    }
  }
  if (lane < 16) {  // g==0: one lane per q-row
    mbuf[zoff + (size_t)bh * 2048 + q0 + w * 16 + l15] = mrow;
    lbuf[zoff + (size_t)bh * 2048 + q0 + w * 16 + l15] = rs;
  }
}

// ---------------------------------------------------------------------------
// combine: oh[row][d] = (w0*O0 + w1*O1) / (w0*l0 + w1*l1), w_z = 2^(m_z - M)
// 131072 threads: thread = (row, 16-d chunk). grid 512, block 256.
// ---------------------------------------------------------------------------
__global__ __launch_bounds__(256) void combine(
    const bf16* __restrict__ Op, const float* __restrict__ mbuf,
    const float* __restrict__ lbuf, bf16* __restrict__ oh) {
  int idx = blockIdx.x * 256 + threadIdx.x;
  int row = idx >> 2;
  int dc = (idx & 3) * 16;
  float m0 = mbuf[row], m1 = mbuf[32768 + row];
  float l0 = lbuf[row], l1 = lbuf[32768 + row];
  float M = fmaxf(m0, m1);
  float w0 = __builtin_amdgcn_exp2f(m0 - M);
  float w1 = __builtin_amdgcn_exp2f(m1 - M);
  float invL = 1.0f / (w0 * l0 + w1 * l1);
  float a0 = w0 * invL, a1 = w1 * invL;

  const bf16x8* p0 = (const bf16x8*)(Op + (size_t)row * 64 + dc);
  const bf16x8* p1 = (const bf16x8*)(Op + (size_t)32768 * 64 + (size_t)row * 64 + dc);
  bf16x8* po = (bf16x8*)(oh + (size_t)row * 64 + dc);
#pragma unroll
  for (int v = 0; v < 2; ++v) {
    bf16x8 x0 = p0[v], x1 = p1[v];
    bf16x8 o;
#pragma unroll
    for (int e = 0; e < 8; ++e)
      o[e] = (bf16)(a0 * (float)x0[e] + a1 * (float)x1[e]);
    po[v] = o;
  }
}

// ---------------------------------------------------------------------------
// out_gemm v2: 128x64 tiles -> grid (4, 32, 2) = 256 blocks (all CUs).
// 4 waves as 2x2 (wave = 64r x 32p, 4x2 frags). BK=32.
// out[b][r][p] = sum_k Wor[r][k] * oh_as_B[p][k] + bo[r]   (fp32 out)
// ---------------------------------------------------------------------------
__global__ __launch_bounds__(256) void out_gemm(
    const bf16* __restrict__ Wor, const bf16* __restrict__ oh,
    const float* __restrict__ bo, float* __restrict__ out) {
  __shared__ bf16 Al[128 * 32];
  __shared__ bf16 Bl[64 * 32];
  int b = blockIdx.z;
  int r0 = blockIdx.x * 128;
  int p0 = blockIdx.y * 64;
  int tid = threadIdx.x, w = tid >> 6, lane = tid & 63;
  int wm = w >> 1, wn = w & 1;
  int g = lane >> 4, l15 = lane & 15;

  const bf16* Abase = Wor + (size_t)r0 * 512;

  f32x4 acc[4][2] = {};

  for (int ks = 0; ks < 16; ++ks) {
    int k0 = ks * 32;
    int hh = k0 >> 6, d0 = k0 & 63;
    const bf16* Bbase = oh + (((size_t)b * 8 + hh) * 2048 + p0) * 64 + d0;
    __syncthreads();
#pragma unroll
    for (int i = 0; i < 2; ++i) {
      int rowl = w * 32 + i * 16 + (lane >> 2);
      gload_lds16(Abase + (size_t)rowl * 512 + k0 + (lane & 3) * 8,
                  Al + (w * 32 + i * 16) * 32);
    }
    {
      int browl = w * 16 + (lane >> 2);
      gload_lds16(Bbase + (size_t)browl * 64 + (lane & 3) * 8,
                  Bl + w * 16 * 32);
    }
    __syncthreads();
    bf16x8 a[4], bb[2];
#pragma unroll
    for (int mi = 0; mi < 4; ++mi)
      a[mi] = *(const bf16x8*)(Al + (wm * 64 + mi * 16 + l15) * 32 + g * 8);
#pragma unroll
    for (int ni = 0; ni < 2; ++ni)
      bb[ni] = *(const bf16x8*)(Bl + (wn * 32 + ni * 16 + l15) * 32 + g * 8);
#pragma unroll
    for (int mi = 0; mi < 4; ++mi)
#pragma unroll
      for (int ni = 0; ni < 2; ++ni)
        acc[mi][ni] = mfma16(a[mi], bb[ni], acc[mi][ni]);
  }

#pragma unroll
  for (int mi = 0; mi < 4; ++mi) {
#pragma unroll
    for (int ni = 0; ni < 2; ++ni) {
#pragma unroll
      for (int r = 0; r < 4; ++r) {
        int row = r0 + wm * 64 + mi * 16 + g * 4 + r;
        int p = p0 + wn * 32 + ni * 16 + l15;
        out[((size_t)b * 512 + row) * 2048 + p] = acc[mi][ni][r] + bo[row];
      }
    }
  }
}

// ---------------------------------------------------------------------------
extern "C" void kernel_launch(void* const* d_in, const int* in_sizes, int n_in,
                              void* d_out, int out_size, void* d_ws, size_t ws_size,
                              hipStream_t stream) {
  (void)in_sizes; (void)n_in; (void)out_size; (void)ws_size;
  const float* Q  = (const float*)d_in[0];
  const float* Wq = (const float*)d_in[1];
  const float* bq = (const float*)d_in[2];
  const float* Wk = (const float*)d_in[3];
  const float* bk = (const float*)d_in[4];
  const float* Wv = (const float*)d_in[5];
  const float* bv = (const float*)d_in[6];
  const float* Wo = (const float*)d_in[7];
  const float* bo = (const float*)d_in[8];
  float* out = (float*)d_out;

  char* ws = (char*)d_ws;
  bf16*  Wf    = (bf16*)(ws + 0);          // 1536*512*2  = 1572864
  bf16*  Wor   = (bf16*)(ws + 1572864);    // 512*512*2   = 524288
  float* biasf = (float*)(ws + 2097152);   // 1536*4      = 6144
  bf16*  Qt    = (bf16*)(ws + 2103296);    // 2*2048*512*2 = 4194304
  bf16*  qp    = (bf16*)(ws + 6297600);    // 4194304
  bf16*  kp    = (bf16*)(ws + 10491904);   // 4194304
  bf16*  vn    = (bf16*)(ws + 14686208);   // 4194304
  bf16*  oh    = (bf16*)(ws + 18880512);   // 4194304  (ends 23074816)
  bf16*  Opart = (bf16*)(ws + 23074816);   // 2*16*2048*64*2 = 8388608
  float* mbuf  = (float*)(ws + 31463424);  // 2*16*2048*4 = 262144
  float* lbuf  = (float*)(ws + 31725568);  // 262144 (ends ~32.0 MB)

  prep_w<<<dim3(2048), dim3(256), 0, stream>>>(Wq, bq, Wk, bk, Wv, bv, Wo,
                                               Wf, biasf, Wor);
  prep_qt<<<dim3(32, 8, 2), dim3(256), 0, stream>>>(Q, Qt);
  qkv_gemm<<<dim3(12, 32, 2), dim3(256), 0, stream>>>(Wf, Qt, biasf, qp, kp, vn);
  attn_k<<<dim3(16, 16, 2), dim3(512), 0, stream>>>(qp, kp, vn, Opart, mbuf, lbuf);
  combine<<<dim3(512), dim3(256), 0, stream>>>(Opart, mbuf, lbuf, oh);
  out_gemm<<<dim3(4, 32, 2), dim3(256), 0, stream>>>(Wor, oh, bo, out);
}